// Round 12
// baseline (1470.356 us; speedup 1.0000x reference)
//
#include <hip/hip_runtime.h>
#include <hip/hip_bf16.h>
#include <hip/hip_fp8.h>

// Problem constants (from reference)
#define NN 50000          // nodes
#define EE 800000         // raw edges
#define E2 850000         // edges + self loops
#define F_IN 128
#define F_HID 64
#define NCHUNK ((NN + 255) / 256)   // 196
#define NTILE  ((NN + 63) / 64)     // 782
#define BA 1024                      // prep blocks  (4 blocks/CU guaranteed)
#define BB 1024                      // layers blocks (4 blocks/CU guaranteed)

__device__ __forceinline__ unsigned char f32_to_fp8(float x) {
    __hip_fp8_e4m3 t(x);              // OCP e4m3fn, saturating
    return t.__x;
}
__device__ __forceinline__ float fp8_to_f32(unsigned char b) {
    __hip_fp8_e4m3 t; t.__x = b;
    return (float)t;
}
__device__ __forceinline__ float readlane_f(float v, int l) {
    return __uint_as_float(__builtin_amdgcn_readlane(__float_as_uint(v), l));
}

// Software global barrier: monotone counter, device-scope atomics,
// threadfence release/acquire (emits L2 writeback/invalidate at agent scope
// -> correct across non-coherent per-XCD L2s). Requires all blocks resident:
// guaranteed by __launch_bounds__(256,4) + LDS<=32KB + grid = 4*256.
__device__ __forceinline__ void gbar(int* cnt, int phase, int nblk) {
    __syncthreads();
    if (threadIdx.x == 0) {
        __threadfence();                         // release
        atomicAdd(cnt, 1);
        int target = phase * nblk;
        while (atomicAdd(cnt, 0) < target) __builtin_amdgcn_s_sleep(2);
        __threadfence();                         // acquire
    }
    __syncthreads();
}

// ---------------------------------------------------------------------------
// PREP megakernel: hist+ei_out -> scan (3 sub-phases) -> bucketed scatter.
// ---------------------------------------------------------------------------
__global__ __launch_bounds__(256, 4) void prep_kernel(const int* __restrict__ ei,
                                                      int* __restrict__ deg,
                                                      float* __restrict__ ei_out,
                                                      int* __restrict__ csum,
                                                      int* __restrict__ offs,
                                                      int* __restrict__ cursor,
                                                      int* __restrict__ src_sorted,
                                                      int* __restrict__ barA) {
    int tid = threadIdx.x;
    int b = blockIdx.x;

    // Phase 1: degree histogram + ei output
    for (int e = b * 256 + tid; e < E2; e += BA * 256) {
        int s, d;
        if (e < EE) { s = ei[e]; d = ei[EE + e]; }
        else        { s = d = e - EE; }
        atomicAdd(&deg[d], 1);
        ei_out[e]      = (float)s;
        ei_out[E2 + e] = (float)d;
    }
    gbar(barA, 1, BA);

    // Phase 2a: per-chunk sums (blocks < NCHUNK)
    if (b < NCHUNK) {
        int i = b * 256 + tid;
        int v = (i < NN) ? deg[i] : 0;
#pragma unroll
        for (int d = 32; d; d >>= 1) v += __shfl_xor(v, d);
        __shared__ int ws4[4];
        if ((tid & 63) == 0) ws4[tid >> 6] = v;
        __syncthreads();
        if (tid == 0) csum[b] = ws4[0] + ws4[1] + ws4[2] + ws4[3];
    }
    gbar(barA, 2, BA);

    // Phase 2b: block 0 scans csum[NCHUNK] exclusive
    if (b == 0) {
        __shared__ int sd[256];
        int v = (tid < NCHUNK) ? csum[tid] : 0;
        sd[tid] = v;
        __syncthreads();
        for (int off = 1; off < 256; off <<= 1) {
            int o = (tid >= off) ? sd[tid - off] : 0;
            __syncthreads();
            sd[tid] += o;
            __syncthreads();
        }
        if (tid < NCHUNK) csum[tid] = sd[tid] - v;
    }
    gbar(barA, 3, BA);

    // Phase 2c: local scan -> offs/cursor (blocks < NCHUNK)
    if (b < NCHUNK) {
        __shared__ int sd2[256];
        int i = b * 256 + tid;
        int v = (i < NN) ? deg[i] : 0;
        sd2[tid] = v;
        __syncthreads();
        for (int off = 1; off < 256; off <<= 1) {
            int o = (tid >= off) ? sd2[tid - off] : 0;
            __syncthreads();
            sd2[tid] += o;
            __syncthreads();
        }
        if (i < NN) {
            int ex = sd2[tid] - v + csum[b];
            offs[i] = ex;
            cursor[i] = ex;
        }
    }
    gbar(barA, 4, BA);

    // Phase 3: bucketed scatter. 1024 blocks = 128 slices x 8 dst-buckets.
    {
        int g = b & 7;
        int slice = b >> 3;
        const int SC = (E2 + 127) / 128;     // 6641
        int begin = slice * SC;
        int end = begin + SC; if (end > E2) end = E2;
        for (int e = begin + tid; e < end; e += 256) {
            int d = (e < EE) ? ei[EE + e] : (e - EE);
            int bucket = (int)(((long long)d * 8) / NN);
            if (bucket == g) {
                int s = (e < EE) ? ei[e] : (e - EE);
                int pos = atomicAdd(&cursor[d], 1);
                src_sorted[pos] = s;
            }
        }
    }
}

// ---------------------------------------------------------------------------
// GEMM phase (device fn): z8 = fp8(h @ W), es/ed fused epilogue.
// W staged in LDS (<=32KB); A rows read direct from global (4-addr coalesced
// broadcast per load). One 64-row tile per block iteration.
// ---------------------------------------------------------------------------
template <int K>
__device__ void gemm_phase(const float* __restrict__ h,
                           const float* __restrict__ W,
                           const float* __restrict__ a_src,
                           const float* __restrict__ a_dst,
                           unsigned char* __restrict__ z8,
                           float* __restrict__ es,
                           float* __restrict__ ed,
                           float* Blds) {
    int tid = threadIdx.x;
    for (int t = tid; t < K * 16; t += 256) {
        float4 v = *(const float4*)(W + t * 4);
        *(float4*)(&Blds[t * 4]) = v;
    }
    __syncthreads();

    int tx = tid & 15;
    int ty = tid >> 4;
    float4 as4 = *(const float4*)(a_src + 4 * tx);
    float4 ad4 = *(const float4*)(a_dst + 4 * tx);

    for (int tile = blockIdx.x; tile < NTILE; tile += BB) {
        int base = tile * 64;
        const float* Ar[4];
#pragma unroll
        for (int i = 0; i < 4; ++i) {
            int gr = base + 4 * ty + i;
            if (gr >= NN) gr = NN - 1;
            Ar[i] = h + (size_t)gr * K;
        }
        float acc[4][4] = {};
#pragma unroll 4
        for (int k = 0; k < K; k += 4) {
            float4 a[4], bb[4];
#pragma unroll
            for (int i = 0; i < 4; ++i) a[i] = *(const float4*)(Ar[i] + k);
#pragma unroll
            for (int kk = 0; kk < 4; ++kk) bb[kk] = *(const float4*)(&Blds[(k + kk) * 64 + 4 * tx]);
#pragma unroll
            for (int i = 0; i < 4; ++i) {
                acc[i][0] = fmaf(a[i].x, bb[0].x, acc[i][0]);
                acc[i][1] = fmaf(a[i].x, bb[0].y, acc[i][1]);
                acc[i][2] = fmaf(a[i].x, bb[0].z, acc[i][2]);
                acc[i][3] = fmaf(a[i].x, bb[0].w, acc[i][3]);
                acc[i][0] = fmaf(a[i].y, bb[1].x, acc[i][0]);
                acc[i][1] = fmaf(a[i].y, bb[1].y, acc[i][1]);
                acc[i][2] = fmaf(a[i].y, bb[1].z, acc[i][2]);
                acc[i][3] = fmaf(a[i].y, bb[1].w, acc[i][3]);
                acc[i][0] = fmaf(a[i].z, bb[2].x, acc[i][0]);
                acc[i][1] = fmaf(a[i].z, bb[2].y, acc[i][1]);
                acc[i][2] = fmaf(a[i].z, bb[2].z, acc[i][2]);
                acc[i][3] = fmaf(a[i].z, bb[2].w, acc[i][3]);
                acc[i][0] = fmaf(a[i].w, bb[3].x, acc[i][0]);
                acc[i][1] = fmaf(a[i].w, bb[3].y, acc[i][1]);
                acc[i][2] = fmaf(a[i].w, bb[3].z, acc[i][2]);
                acc[i][3] = fmaf(a[i].w, bb[3].w, acc[i][3]);
            }
        }
        float ps[4], pd[4];
#pragma unroll
        for (int i = 0; i < 4; ++i) {
            int gr = base + 4 * ty + i;
            if (gr < NN) {
                unsigned int pk = (unsigned int)f32_to_fp8(acc[i][0])
                                | ((unsigned int)f32_to_fp8(acc[i][1]) << 8)
                                | ((unsigned int)f32_to_fp8(acc[i][2]) << 16)
                                | ((unsigned int)f32_to_fp8(acc[i][3]) << 24);
                *(unsigned int*)(&z8[(size_t)gr * 64 + 4 * tx]) = pk;
            }
            ps[i] = acc[i][0] * as4.x + acc[i][1] * as4.y + acc[i][2] * as4.z + acc[i][3] * as4.w;
            pd[i] = acc[i][0] * ad4.x + acc[i][1] * ad4.y + acc[i][2] * ad4.z + acc[i][3] * ad4.w;
        }
#pragma unroll
        for (int d = 1; d < 16; d <<= 1) {
#pragma unroll
            for (int i = 0; i < 4; ++i) {
                ps[i] += __shfl_xor(ps[i], d);
                pd[i] += __shfl_xor(pd[i], d);
            }
        }
        if (tx == 0) {
#pragma unroll
            for (int i = 0; i < 4; ++i) {
                int gr = base + 4 * ty + i;
                if (gr < NN) { es[gr] = ps[i]; ed[gr] = pd[i]; }
            }
        }
    }
}

// ---------------------------------------------------------------------------
// Aggregation phase (device fn): pipelined multi-node, lane-parallel weight
// batches + readlane broadcast + one 64B z8-row gather per edge.
// ---------------------------------------------------------------------------
__device__ void agg_phase(const int* __restrict__ offs,
                          const int* __restrict__ deg,
                          const int* __restrict__ src_sorted,
                          const float* __restrict__ es,
                          const float* __restrict__ ed,
                          const unsigned char* __restrict__ z8,
                          const float* __restrict__ bias,
                          float* __restrict__ hout,
                          float* __restrict__ denom_out) {
    int tid = threadIdx.x;
    int lane = tid & 63;
    int wave = blockIdx.x * 4 + (tid >> 6);
    const int NW = BB * 4;
    float bi = bias[lane];

    int n = wave;
    if (n >= NN) return;
    n = __builtin_amdgcn_readfirstlane(n);
    int off = offs[n];
    int dg = deg[n];
    float edn = ed[n];
    int sv = src_sorted[off + ((lane < dg) ? lane : 0)];

    while (true) {
        int n2 = n + NW;
        bool more = (n2 < NN);
        int off2 = 0, dg2 = 0; float edn2 = 0.f;
        if (more) {
            n2 = __builtin_amdgcn_readfirstlane(n2);
            off2 = offs[n2]; dg2 = deg[n2]; edn2 = ed[n2];
        }

        float dsum = 0.f;
        float a0 = 0.f, a1 = 0.f, a2 = 0.f, a3 = 0.f;
        float a4 = 0.f, a5 = 0.f, a6 = 0.f, a7 = 0.f;
        for (int b0 = 0; b0 < dg; b0 += 64) {
            int bl = dg - b0; if (bl > 64) bl = 64;
            int svb = (b0 == 0) ? sv
                                : src_sorted[off + b0 + ((lane < bl) ? lane : 0)];
            float e = es[svb] + edn;
            e = (e > 0.f) ? e : 0.2f * e;
            float w = (lane < bl) ? __expf(e) : 0.f;
            dsum += w;

            int j = 0;
            for (; j + 8 <= bl; j += 8) {
                int   s0 = __builtin_amdgcn_readlane(svb, j);
                int   s1 = __builtin_amdgcn_readlane(svb, j + 1);
                int   s2 = __builtin_amdgcn_readlane(svb, j + 2);
                int   s3 = __builtin_amdgcn_readlane(svb, j + 3);
                int   s4 = __builtin_amdgcn_readlane(svb, j + 4);
                int   s5 = __builtin_amdgcn_readlane(svb, j + 5);
                int   s6 = __builtin_amdgcn_readlane(svb, j + 6);
                int   s7 = __builtin_amdgcn_readlane(svb, j + 7);
                float w0 = readlane_f(w, j),     w1 = readlane_f(w, j + 1);
                float w2 = readlane_f(w, j + 2), w3 = readlane_f(w, j + 3);
                float w4 = readlane_f(w, j + 4), w5 = readlane_f(w, j + 5);
                float w6 = readlane_f(w, j + 6), w7 = readlane_f(w, j + 7);
                a0 = fmaf(w0, fp8_to_f32(z8[(size_t)s0 * 64 + lane]), a0);
                a1 = fmaf(w1, fp8_to_f32(z8[(size_t)s1 * 64 + lane]), a1);
                a2 = fmaf(w2, fp8_to_f32(z8[(size_t)s2 * 64 + lane]), a2);
                a3 = fmaf(w3, fp8_to_f32(z8[(size_t)s3 * 64 + lane]), a3);
                a4 = fmaf(w4, fp8_to_f32(z8[(size_t)s4 * 64 + lane]), a4);
                a5 = fmaf(w5, fp8_to_f32(z8[(size_t)s5 * 64 + lane]), a5);
                a6 = fmaf(w6, fp8_to_f32(z8[(size_t)s6 * 64 + lane]), a6);
                a7 = fmaf(w7, fp8_to_f32(z8[(size_t)s7 * 64 + lane]), a7);
            }
            for (; j + 4 <= bl; j += 4) {
                int   s0 = __builtin_amdgcn_readlane(svb, j);
                int   s1 = __builtin_amdgcn_readlane(svb, j + 1);
                int   s2 = __builtin_amdgcn_readlane(svb, j + 2);
                int   s3 = __builtin_amdgcn_readlane(svb, j + 3);
                float w0 = readlane_f(w, j),     w1 = readlane_f(w, j + 1);
                float w2 = readlane_f(w, j + 2), w3 = readlane_f(w, j + 3);
                a0 = fmaf(w0, fp8_to_f32(z8[(size_t)s0 * 64 + lane]), a0);
                a1 = fmaf(w1, fp8_to_f32(z8[(size_t)s1 * 64 + lane]), a1);
                a2 = fmaf(w2, fp8_to_f32(z8[(size_t)s2 * 64 + lane]), a2);
                a3 = fmaf(w3, fp8_to_f32(z8[(size_t)s3 * 64 + lane]), a3);
            }
            for (; j < bl; ++j) {
                int   s0 = __builtin_amdgcn_readlane(svb, j);
                float w0 = readlane_f(w, j);
                a0 = fmaf(w0, fp8_to_f32(z8[(size_t)s0 * 64 + lane]), a0);
            }
        }

        int sv2 = 0;
        if (more) sv2 = src_sorted[off2 + ((lane < dg2) ? lane : 0)];

#pragma unroll
        for (int d = 32; d; d >>= 1) dsum += __shfl_xor(dsum, d);
        float acc = ((a0 + a1) + (a2 + a3)) + ((a4 + a5) + (a6 + a7));
        float inv = 1.f / (dsum + 1e-16f);
        float o = acc * inv + bi;
        o = (o > 0.f) ? o : 0.01f * o;
        hout[(size_t)n * 64 + lane] = o;
        if (lane == 0) denom_out[n] = dsum;

        if (!more) break;
        n = n2; off = off2; dg = dg2; edn = edn2; sv = sv2;
    }
}

// ---------------------------------------------------------------------------
// LAYERS megakernel: (gemm -> agg) x3 -> alpha, global barriers between.
// ---------------------------------------------------------------------------
__global__ __launch_bounds__(256, 4) void layers_kernel(
        const float* __restrict__ x,
        const float* __restrict__ W1, const float* __restrict__ as1,
        const float* __restrict__ ad1, const float* __restrict__ b1,
        const float* __restrict__ W2, const float* __restrict__ as2,
        const float* __restrict__ ad2, const float* __restrict__ b2,
        const float* __restrict__ W3, const float* __restrict__ as3,
        const float* __restrict__ ad3, const float* __restrict__ b3,
        const int* __restrict__ ei,
        const int* __restrict__ offs, const int* __restrict__ deg,
        const int* __restrict__ src_sorted,
        unsigned char* __restrict__ z8, float* __restrict__ es,
        float* __restrict__ ed, float* __restrict__ denom,
        float* __restrict__ h1, float* __restrict__ h2,
        float* __restrict__ h_out, float* __restrict__ alpha_out,
        int* __restrict__ barB) {
    __shared__ float Blds[F_IN * 64];   // 32 KB, reused by all gemm phases

    gemm_phase<F_IN>(x, W1, as1, ad1, z8, es, ed, Blds);
    gbar(barB, 1, BB);
    agg_phase(offs, deg, src_sorted, es, ed, z8, b1, h1, denom);
    gbar(barB, 2, BB);

    gemm_phase<F_HID>(h1, W2, as2, ad2, z8, es, ed, Blds);
    gbar(barB, 3, BB);
    agg_phase(offs, deg, src_sorted, es, ed, z8, b2, h2, denom);
    gbar(barB, 4, BB);

    gemm_phase<F_HID>(h2, W3, as3, ad3, z8, es, ed, Blds);
    gbar(barB, 5, BB);
    agg_phase(offs, deg, src_sorted, es, ed, z8, b3, h_out, denom);
    gbar(barB, 6, BB);

    // Alpha in original edge order (contiguous writes)
    int tid = threadIdx.x;
    for (int e = blockIdx.x * 256 + tid; e < E2; e += BB * 256) {
        int s, d;
        if (e < EE) { s = ei[e]; d = ei[EE + e]; }
        else        { s = d = e - EE; }
        float xx = es[s] + ed[d];
        xx = (xx > 0.f) ? xx : 0.2f * xx;
        alpha_out[e] = __expf(xx) / (denom[d] + 1e-16f);
    }
}

// ---------------------------------------------------------------------------
extern "C" void kernel_launch(void* const* d_in, const int* in_sizes, int n_in,
                              void* d_out, int out_size, void* d_ws, size_t ws_size,
                              hipStream_t stream) {
    const float* x   = (const float*)d_in[0];
    const int*   ei  = (const int*)d_in[1];
    const float* W1  = (const float*)d_in[2];
    const float* as1 = (const float*)d_in[3];
    const float* ad1 = (const float*)d_in[4];
    const float* b1  = (const float*)d_in[5];
    const float* W2  = (const float*)d_in[6];
    const float* as2 = (const float*)d_in[7];
    const float* ad2 = (const float*)d_in[8];
    const float* b2  = (const float*)d_in[9];
    const float* W3  = (const float*)d_in[10];
    const float* as3 = (const float*)d_in[11];
    const float* ad3 = (const float*)d_in[12];
    const float* b3  = (const float*)d_in[13];

    // d_out is float32: h | ei | alpha, flat.
    float* out       = (float*)d_out;
    float* h_out     = out;                                // NN*64
    float* ei_out    = out + (size_t)NN * 64;              // 2*E2
    float* alpha_out = ei_out + 2 * (size_t)E2;            // E2

    // Workspace carve-up
    char* w = (char*)d_ws;
    auto carve = [&](size_t bytes) {
        void* p = (void*)w;
        w += (bytes + 255) & ~size_t(255);
        return p;
    };
    float* h1  = (float*)carve((size_t)NN * 64 * 4);
    float* h2  = (float*)carve((size_t)NN * 64 * 4);
    unsigned char* z8 = (unsigned char*)carve((size_t)NN * 64);
    float* es  = (float*)carve((size_t)NN * 4);
    float* ed  = (float*)carve((size_t)NN * 4);
    float* denom = (float*)carve((size_t)NN * 4);
    int* deg        = (int*)carve(((size_t)NN + 64) * 4);  // deg + barriers, zeroed together
    int* barA       = deg + NN;
    int* barB       = deg + NN + 1;
    int* offs       = (int*)carve((size_t)NN * 4);
    int* cursor     = (int*)carve((size_t)NN * 4);
    int* csum       = (int*)carve((size_t)NCHUNK * 4);
    int* src_sorted = (int*)carve((size_t)E2 * 4);

    hipMemsetAsync(deg, 0, ((size_t)NN + 64) * 4, stream);
    prep_kernel<<<BA, 256, 0, stream>>>(ei, deg, ei_out, csum, offs, cursor,
                                        src_sorted, barA);
    layers_kernel<<<BB, 256, 0, stream>>>(x,
                                          W1, as1, ad1, b1,
                                          W2, as2, ad2, b2,
                                          W3, as3, ad3, b3,
                                          ei, offs, deg, src_sorted,
                                          z8, es, ed, denom,
                                          h1, h2, h_out, alpha_out, barB);
}